// Round 4
// baseline (402.288 us; speedup 1.0000x reference)
//
#include <hip/hip_runtime.h>
#include <math.h>

// SE4 squeeze-excite, B=8, C=64, H=W=256, 4x4 patch grid (64x64 patches), SQ=256.
// ALL I/O float32. fp32 compute.
//
// R7: single fused kernel with a SOFTWARE grid barrier (R6's
// hipLaunchCooperativeKernel silently failed in this harness: absmax == max|ref|,
// i.e. out stayed memset-zero).
//  - 512 blocks x 256 threads, __launch_bounds__(256,2) -> 2 blocks/CU, half of
//    co-residency capacity (sanctioned persistent-grid pattern, no deadlock margin).
//  - Barrier state in __device__ globals (zero-init, self-restoring across
//    launches: counters return to 0, generation monotonically counts). Immune to
//    workspace poison. Two-level arrival tree (8 padded leaves x 64 + root) to
//    bound same-address atomic serialization; AGENT-scope acquire/release for
//    cross-XCD visibility.
//  - Phase 4 nontemporal-stores out so phase-1's t read stays L3-resident.

#define Bsz 8
#define Csz 64
#define Hsz 256
#define Wsz 256
#define SQsz 256
#define C16 1024   // 16*C
#define NBLK 512

typedef float f32x4 __attribute__((ext_vector_type(4)));

__device__ __attribute__((aligned(128))) unsigned g_leaf[8][32]; // [i][0] used, 128B padded
__device__ unsigned g_root = 0;
__device__ unsigned g_gen  = 0;

__device__ __forceinline__ void grid_barrier(int bid) {
    __syncthreads();
    if (threadIdx.x == 0) {
        __threadfence();   // prior writes device-visible before arrival
        unsigned g0 = __hip_atomic_load(&g_gen, __ATOMIC_ACQUIRE, __HIP_MEMORY_SCOPE_AGENT);
        int leaf = bid & 7;
        unsigned a = __hip_atomic_fetch_add(&g_leaf[leaf][0], 1u,
                                            __ATOMIC_ACQ_REL, __HIP_MEMORY_SCOPE_AGENT);
        bool last = false;
        if (a == 63u) {                    // 512/8 = 64 arrivals per leaf
            unsigned r = __hip_atomic_fetch_add(&g_root, 1u,
                                                __ATOMIC_ACQ_REL, __HIP_MEMORY_SCOPE_AGENT);
            if (r == 7u) {
                for (int i = 0; i < 8; ++i)
                    __hip_atomic_store(&g_leaf[i][0], 0u, __ATOMIC_RELAXED, __HIP_MEMORY_SCOPE_AGENT);
                __hip_atomic_store(&g_root, 0u, __ATOMIC_RELAXED, __HIP_MEMORY_SCOPE_AGENT);
                __hip_atomic_fetch_add(&g_gen, 1u, __ATOMIC_RELEASE, __HIP_MEMORY_SCOPE_AGENT);
                last = true;
            }
        }
        if (!last) {
            while (__hip_atomic_load(&g_gen, __ATOMIC_ACQUIRE, __HIP_MEMORY_SCOPE_AGENT) == g0)
                __builtin_amdgcn_s_sleep(2);
        }
    }
    __syncthreads();
}

__global__ __launch_bounds__(256, 2) void fused_kernel(
    const float* __restrict__ t,
    const float* __restrict__ reduce_w,
    const float* __restrict__ reduce_b,
    const float* __restrict__ expand_w,
    const float* __restrict__ expand_b,
    float* __restrict__ out,
    float* __restrict__ ws)
{
    float* pooled = ws;                     // 8*1024 fp32 = 32 KB
    float* s_buf  = ws + Bsz * C16;         // 8*256  fp32 =  8 KB
    float* g_buf  = s_buf + Bsz * SQsz;     // 8*1024 fp32 = 32 KB

    const int bid  = blockIdx.x;            // 0..511
    const int tid  = threadIdx.x;           // 0..255
    const int lane = tid & 63;
    const int wid  = tid >> 6;              // wave 0..3

    // ---------- phase 1: patch pooling ----------
    // One block per (b,c) channel (512 = 8*64). Wave wid owns patch-row i=wid
    // (rows 64*wid..64*wid+63); lane l owns col4=l (j = l>>4). 64 fully-coalesced
    // 1KB row reads per wave; 16-lane segmented butterfly -> psum[i][j] complete.
    {
        const float* base = t + (size_t)bid * (Hsz * Wsz);
        float a = 0.f;
#pragma unroll 8
        for (int r = 0; r < 64; ++r) {
            f32x4 v = *(const f32x4*)(base + (size_t)(wid * 64 + r) * Wsz + lane * 4);
            a += v.x + v.y + v.z + v.w;
        }
#pragma unroll
        for (int m = 8; m >= 1; m >>= 1) a += __shfl_xor(a, m, 64);
        __shared__ float psum[4][4];
        if ((lane & 15) == 0) psum[wid][lane >> 4] = a;
        __syncthreads();
        if (tid < 16) {
            int b = bid >> 6, c = bid & 63;
            pooled[b * C16 + tid * Csz + c] = psum[tid >> 2][tid & 3] * (1.0f / 4096.0f);
        }
    }
    grid_barrier(bid);

    // ---------- phase 2: s = mish(pooled @ reduce_w^T + reduce_b) ----------
    // Blocks 0..255: one output o per block; thread tid owns float4 k-chunk tid.
    if (bid < SQsz) {
        const int o = bid;
        f32x4 wv = ((const f32x4*)(reduce_w + (size_t)o * C16))[tid];
        float acc[Bsz];
#pragma unroll
        for (int b = 0; b < Bsz; ++b) {
            f32x4 pv = ((const f32x4*)pooled)[b * 256 + tid];
            acc[b] = wv.x * pv.x + wv.y * pv.y + wv.z * pv.z + wv.w * pv.w;
        }
#pragma unroll
        for (int off = 32; off >= 1; off >>= 1) {
#pragma unroll
            for (int b = 0; b < Bsz; ++b)
                acc[b] += __shfl_xor(acc[b], off, 64);
        }
        __shared__ float cr[4][8];
        if (lane == 0) {
#pragma unroll
            for (int b = 0; b < Bsz; ++b) cr[wid][b] = acc[b];
        }
        __syncthreads();
        if (tid < Bsz) {
            float x = reduce_b[o] + cr[0][tid] + cr[1][tid] + cr[2][tid] + cr[3][tid];
            float sp = (x > 15.f) ? x : log1pf(expf(x));
            s_buf[tid * SQsz + o] = x * tanhf(sp);
        }
    }
    grid_barrier(bid);

    // ---------- phase 3: g = sigmoid(s @ expand_w^T + expand_b) ----------
    // 1024 outputs over 512 blocks: o0 = 2*bid, o1 = 2*bid+1. k = tid (K=256).
    {
        const int o0 = bid * 2, o1 = o0 + 1;
        float wv0 = expand_w[(size_t)o0 * SQsz + tid];
        float wv1 = expand_w[(size_t)o1 * SQsz + tid];
        float acc0[Bsz], acc1[Bsz];
#pragma unroll
        for (int b = 0; b < Bsz; ++b) {
            float sv = s_buf[b * SQsz + tid];
            acc0[b] = wv0 * sv;
            acc1[b] = wv1 * sv;
        }
#pragma unroll
        for (int off = 32; off >= 1; off >>= 1) {
#pragma unroll
            for (int b = 0; b < Bsz; ++b) {
                acc0[b] += __shfl_xor(acc0[b], off, 64);
                acc1[b] += __shfl_xor(acc1[b], off, 64);
            }
        }
        __shared__ float cr0[4][8], cr1[4][8];
        if (lane == 0) {
#pragma unroll
            for (int b = 0; b < Bsz; ++b) { cr0[wid][b] = acc0[b]; cr1[wid][b] = acc1[b]; }
        }
        __syncthreads();
        if (tid < Bsz) {
            float x = expand_b[o0] + cr0[0][tid] + cr0[1][tid] + cr0[2][tid] + cr0[3][tid];
            g_buf[tid * C16 + o0] = 1.0f / (1.0f + expf(-x));
        } else if (tid >= 64 && tid < 64 + Bsz) {
            int b = tid - 64;
            float x = expand_b[o1] + cr1[0][b] + cr1[1][b] + cr1[2][b] + cr1[3][b];
            g_buf[b * C16 + o1] = 1.0f / (1.0f + expf(-x));
        }
    }
    grid_barrier(bid);

    // ---------- phase 4: out = t * gate ----------
    // Grid-stride over 8,388,608 float4 groups (64 iters/thread). t is
    // L3-resident from phase 1; gates (32 KB) L2-hot. Nontemporal stores keep
    // out from evicting t.
#pragma unroll 8
    for (int it = 0; it < 64; ++it) {
        unsigned int idx = (unsigned int)(it * NBLK + bid) * 256u + tid;  // float4 index
        int w4 = idx & 63;
        int h  = (idx >> 6) & 255;
        int c  = (idx >> 14) & 63;
        int b  = idx >> 20;
        int p  = ((h >> 6) << 2) | (w4 >> 4);
        float gate = g_buf[(b << 10) + (p << 6) + c];
        f32x4 v = *(const f32x4*)(t + (size_t)idx * 4);
        f32x4 r;
        r.x = v.x * gate;
        r.y = v.y * gate;
        r.z = v.z * gate;
        r.w = v.w * gate;
        __builtin_nontemporal_store(r, (f32x4*)(out + (size_t)idx * 4));
    }
}

extern "C" void kernel_launch(void* const* d_in, const int* in_sizes, int n_in,
                              void* d_out, int out_size, void* d_ws, size_t ws_size,
                              hipStream_t stream) {
    const float* t        = (const float*)d_in[0];
    const float* reduce_w = (const float*)d_in[1];
    const float* reduce_b = (const float*)d_in[2];
    const float* expand_w = (const float*)d_in[3];
    const float* expand_b = (const float*)d_in[4];
    float* out = (float*)d_out;
    float* ws  = (float*)d_ws;

    fused_kernel<<<NBLK, 256, 0, stream>>>(t, reduce_w, reduce_b,
                                           expand_w, expand_b, out, ws);
}

// Round 5
// 262.354 us; speedup vs baseline: 1.5334x; 1.5334x over previous
//
#include <hip/hip_runtime.h>
#include <math.h>

// SE4 squeeze-excite, B=8, C=64, H=W=256, 4x4 patch grid (64x64 patches), SQ=256.
// ALL I/O float32. fp32 compute.
//
// R8: revert to the proven 4-kernel pipeline (R5 = 260 us; fused R7 = 402 us).
// Accounting closed by R7's counters: ~158 us of the window is two 512-MiB
// harness poison fills (fixed); our 4 kernels + gaps are ~100 us vs ~70 floor.
// Single change vs R5: scale_kernel now does 4 float4 per thread (8192 blocks),
// unrolled -> 4 independent load+store pairs in flight per wave (R5 had 1).
// t's second read is L3-hit (R7: FETCH=132MB total for both passes).

#define Bsz 8
#define Csz 64
#define Hsz 256
#define Wsz 256
#define SQsz 256
#define C16 1024   // 16*C

typedef float f32x4 __attribute__((ext_vector_type(4)));

// ---------------- kernel 1: patch pooling ----------------
// grid = B*C*16 = 8192 blocks of 256 threads. p = bid & 15 (= i*4+j), bc = bid>>4.
// Patch: 64 rows x 64 cols fp32 = 1024 float4 groups; each thread sums 4 groups.
// Regular (caching) loads on purpose: t must land in L3 for scale_kernel.
__global__ __launch_bounds__(256) void pool_kernel(const float* __restrict__ t,
                                                   float* __restrict__ pooled) {
    int bid = blockIdx.x;
    int p   = bid & 15;
    int bc  = bid >> 4;          // b*C + c
    int i   = p >> 2, j = p & 3;
    const float* base = t + (((size_t)bc * Hsz + (size_t)i * 64) * Wsz + (size_t)j * 64);
    int tid = threadIdx.x;
    float sum = 0.f;
#pragma unroll
    for (int k = 0; k < 4; ++k) {
        int g    = tid + k * 256;          // 0..1023
        int row  = g >> 4;
        int col4 = g & 15;
        f32x4 v = *(const f32x4*)(base + (size_t)row * Wsz + col4 * 4);
        sum += v.x + v.y + v.z + v.w;
    }
#pragma unroll
    for (int off = 32; off > 0; off >>= 1) sum += __shfl_down(sum, off, 64);
    __shared__ float wsum[4];
    if ((tid & 63) == 0) wsum[tid >> 6] = sum;
    __syncthreads();
    if (tid == 0) {
        float s = wsum[0] + wsum[1] + wsum[2] + wsum[3];
        int b = bc >> 6;          // /C
        int c = bc & 63;
        pooled[b * C16 + p * Csz + c] = s * (1.0f / 4096.0f);
    }
}

// ---------------- kernel 2: s = mish(pooled @ reduce_w^T + reduce_b) ----------------
// grid = 256 blocks (one per output o) x 1024 threads: k = tid, one element per
// thread, 9-deep chain, 16 waves/CU.
__global__ __launch_bounds__(1024) void reduce_kernel(const float* __restrict__ pooled,
                                                      const float* __restrict__ reduce_w,
                                                      const float* __restrict__ reduce_b,
                                                      float* __restrict__ s_out) {
    int o   = blockIdx.x;
    int tid = threadIdx.x;          // 0..1023 == k
    int w   = tid >> 6;             // wave 0..15
    int l   = tid & 63;
    float wv = reduce_w[(size_t)o * C16 + tid];
    float acc[Bsz];
#pragma unroll
    for (int b = 0; b < Bsz; ++b)
        acc[b] = wv * pooled[b * C16 + tid];
#pragma unroll
    for (int off = 32; off > 0; off >>= 1) {
#pragma unroll
        for (int b = 0; b < Bsz; ++b)
            acc[b] += __shfl_xor(acc[b], off, 64);
    }
    __shared__ float red[16][Bsz];
    if (l == 0) {
#pragma unroll
        for (int b = 0; b < Bsz; ++b) red[w][b] = acc[b];
    }
    __syncthreads();
    if (tid < Bsz) {
        float x = reduce_b[o];
#pragma unroll
        for (int q = 0; q < 16; ++q) x += red[q][tid];
        float sp = (x > 15.f) ? x : log1pf(expf(x));
        s_out[tid * SQsz + o] = x * tanhf(sp);
    }
}

// ---------------- kernel 3: g = sigmoid(s @ expand_w^T + expand_b) ----------------
// grid = 1024 blocks (one per output o) x 256 threads: k = tid, 9-deep chain,
// 4 blocks/CU x 4 waves = 16 waves/CU.
__global__ __launch_bounds__(256) void expand_kernel(const float* __restrict__ s_in,
                                                     const float* __restrict__ expand_w,
                                                     const float* __restrict__ expand_b,
                                                     float* __restrict__ g_out) {
    int o   = blockIdx.x;
    int tid = threadIdx.x;          // 0..255 == k
    int w   = tid >> 6;             // wave 0..3
    int l   = tid & 63;
    float wv = expand_w[(size_t)o * SQsz + tid];
    float acc[Bsz];
#pragma unroll
    for (int b = 0; b < Bsz; ++b)
        acc[b] = wv * s_in[b * SQsz + tid];
#pragma unroll
    for (int off = 32; off > 0; off >>= 1) {
#pragma unroll
        for (int b = 0; b < Bsz; ++b)
            acc[b] += __shfl_xor(acc[b], off, 64);
    }
    __shared__ float red[4][Bsz];
    if (l == 0) {
#pragma unroll
        for (int b = 0; b < Bsz; ++b) red[w][b] = acc[b];
    }
    __syncthreads();
    if (tid < Bsz) {
        float x = expand_b[o] + red[0][tid] + red[1][tid] + red[2][tid] + red[3][tid];
        g_out[tid * C16 + o] = 1.0f / (1.0f + expf(-x));
    }
}

// ---------------- kernel 4: out = t * gate ----------------
// R8: 4 float4 groups per thread, 8192 blocks x 256. Block covers 1024
// contiguous float4s (16 KB); iteration it handles a fully-coalesced 1-KB/wave
// slab. 4 independent {gate-load, t-load, NT-store} chains in flight per wave
// (vs 1 in R5). t load hits L3 (resident from pool); NT load marks it
// evict-first (dead after this read); NT store keeps out from evicting t.
__global__ __launch_bounds__(256) void scale_kernel(const float* __restrict__ t,
                                                    const float* __restrict__ g,
                                                    float* __restrict__ out) {
    unsigned int base = blockIdx.x * 1024u + threadIdx.x;   // float4 group index
#pragma unroll
    for (int it = 0; it < 4; ++it) {
        unsigned int idx = base + (unsigned int)it * 256u;
        int w4 = idx & 63;                // w/4
        int h  = (idx >> 6) & 255;
        int c  = (idx >> 14) & 63;
        int b  = idx >> 20;
        int p  = ((h >> 6) << 2) | (w4 >> 4);    // i*4 + j
        float gate = g[(b << 10) + (p << 6) + c];
        f32x4 v = __builtin_nontemporal_load((const f32x4*)(t + (size_t)idx * 4));
        f32x4 r;
        r.x = v.x * gate;
        r.y = v.y * gate;
        r.z = v.z * gate;
        r.w = v.w * gate;
        __builtin_nontemporal_store(r, (f32x4*)(out + (size_t)idx * 4));
    }
}

extern "C" void kernel_launch(void* const* d_in, const int* in_sizes, int n_in,
                              void* d_out, int out_size, void* d_ws, size_t ws_size,
                              hipStream_t stream) {
    const float* t        = (const float*)d_in[0];
    const float* reduce_w = (const float*)d_in[1];
    const float* reduce_b = (const float*)d_in[2];
    const float* expand_w = (const float*)d_in[3];
    const float* expand_b = (const float*)d_in[4];
    float* out = (float*)d_out;

    float* pooled = (float*)d_ws;                 // 8*1024 fp32 = 32 KB
    float* s_buf  = pooled + Bsz * C16;           // 8*256  fp32 =  8 KB
    float* g_buf  = s_buf + Bsz * SQsz;           // 8*1024 fp32 = 32 KB

    pool_kernel  <<<Bsz * Csz * 16, 256, 0, stream>>>(t, pooled);
    reduce_kernel<<<SQsz,          1024, 0, stream>>>(pooled, reduce_w, reduce_b, s_buf);
    expand_kernel<<<C16,            256, 0, stream>>>(s_buf, expand_w, expand_b, g_buf);
    scale_kernel <<<8192,           256, 0, stream>>>(t, g_buf, out);
}

// Round 6
// 260.603 us; speedup vs baseline: 1.5437x; 1.0067x over previous
//
#include <hip/hip_runtime.h>
#include <math.h>

// SE4 squeeze-excite, B=8, C=64, H=W=256, 4x4 patch grid (64x64 patches), SQ=256.
// ALL I/O float32. fp32 compute.
//
// R9: 3-kernel pipeline. Accounting (R7 counters): window = ~158us fixed harness
// poison fills + ~100us of our kernels+gaps. Changes vs best (R3, 257.5us):
//  - expand_kernel DELETED: scale blocks recompute their 4 gates in-block
//    (4 x 256-dot over L2-hot s_buf + expand_w rows; 41 MB L2 total ~1.2us).
//    Saves a launch + gap + the g_buf write/read round-trip.
//  - NT loads/stores REVERTED (R5/R8 showed them mildly negative: nt bypasses
//    L3, defeating the L3-hit on t's second read that R7 proved: FETCH=132MB
//    total across both passes).

#define Bsz 8
#define Csz 64
#define Hsz 256
#define Wsz 256
#define SQsz 256
#define C16 1024   // 16*C

typedef float f32x4 __attribute__((ext_vector_type(4)));

// ---------------- kernel 1: patch pooling ----------------
// grid = B*C*16 = 8192 blocks of 256 threads. p = bid & 15 (= i*4+j), bc = bid>>4.
// Patch: 64 rows x 64 cols fp32 = 1024 float4 groups; each thread sums 4 groups.
// Regular (caching) loads on purpose: t must land in L3 for scale_kernel.
__global__ __launch_bounds__(256) void pool_kernel(const float* __restrict__ t,
                                                   float* __restrict__ pooled) {
    int bid = blockIdx.x;
    int p   = bid & 15;
    int bc  = bid >> 4;          // b*C + c
    int i   = p >> 2, j = p & 3;
    const float* base = t + (((size_t)bc * Hsz + (size_t)i * 64) * Wsz + (size_t)j * 64);
    int tid = threadIdx.x;
    float sum = 0.f;
#pragma unroll
    for (int k = 0; k < 4; ++k) {
        int g    = tid + k * 256;          // 0..1023
        int row  = g >> 4;
        int col4 = g & 15;
        f32x4 v = *(const f32x4*)(base + (size_t)row * Wsz + col4 * 4);
        sum += v.x + v.y + v.z + v.w;
    }
#pragma unroll
    for (int off = 32; off > 0; off >>= 1) sum += __shfl_down(sum, off, 64);
    __shared__ float wsum[4];
    if ((tid & 63) == 0) wsum[tid >> 6] = sum;
    __syncthreads();
    if (tid == 0) {
        float s = wsum[0] + wsum[1] + wsum[2] + wsum[3];
        int b = bc >> 6;          // /C
        int c = bc & 63;
        pooled[b * C16 + p * Csz + c] = s * (1.0f / 4096.0f);
    }
}

// ---------------- kernel 2: s = mish(pooled @ reduce_w^T + reduce_b) ----------------
// grid = 256 blocks (one per output o) x 1024 threads: k = tid, one element per
// thread, 9-deep chain, 16 waves/CU. s layout: s_buf[b*256 + o].
__global__ __launch_bounds__(1024) void reduce_kernel(const float* __restrict__ pooled,
                                                      const float* __restrict__ reduce_w,
                                                      const float* __restrict__ reduce_b,
                                                      float* __restrict__ s_out) {
    int o   = blockIdx.x;
    int tid = threadIdx.x;          // 0..1023 == k
    int w   = tid >> 6;             // wave 0..15
    int l   = tid & 63;
    float wv = reduce_w[(size_t)o * C16 + tid];
    float acc[Bsz];
#pragma unroll
    for (int b = 0; b < Bsz; ++b)
        acc[b] = wv * pooled[b * C16 + tid];
#pragma unroll
    for (int off = 32; off > 0; off >>= 1) {
#pragma unroll
        for (int b = 0; b < Bsz; ++b)
            acc[b] += __shfl_xor(acc[b], off, 64);
    }
    __shared__ float red[16][Bsz];
    if (l == 0) {
#pragma unroll
        for (int b = 0; b < Bsz; ++b) red[w][b] = acc[b];
    }
    __syncthreads();
    if (tid < Bsz) {
        float x = reduce_b[o];
#pragma unroll
        for (int q = 0; q < 16; ++q) x += red[q][tid];
        float sp = (x > 15.f) ? x : log1pf(expf(x));
        s_out[tid * SQsz + o] = x * tanhf(sp);
    }
}

// ---------------- kernel 3: out = t * sigmoid(s @ expand_w^T + expand_b) ----------------
// grid = 8192 blocks x 256 threads. Block covers 4096 contiguous floats =
// 16 h-rows, aligned -> single (b, c, i); only 4 gates needed (j = 0..3).
// Gate recompute in-block: thread tid holds k=tid; 4 dots over L2-hot
// s_buf row (1 KB) and expand_w rows (4 KB); butterfly + LDS combine.
// Then 4 streaming float4 iterations; w4 = tid&63 (const across iters), so
// each thread uses ONE gate, read once from LDS.
__global__ __launch_bounds__(256) void scale_kernel(const float* __restrict__ t,
                                                    const float* __restrict__ s_buf,
                                                    const float* __restrict__ expand_w,
                                                    const float* __restrict__ expand_b,
                                                    float* __restrict__ out) {
    int bid  = blockIdx.x;               // 0..8191
    int tid  = threadIdx.x;              // 0..255
    int lane = tid & 63;
    int wid  = tid >> 6;

    unsigned int base_f4 = (unsigned int)bid * 1024u;   // float4 group index base
    int b  = base_f4 >> 20;                             // 2^20 f4 per batch
    int c  = (base_f4 >> 14) & 63;                      // 2^14 f4 per channel
    int i  = ((base_f4 >> 6) & 255) >> 6;               // patch-row of this slab

    // ---- gate recompute: o_j = (i*4+j)*64 + c, j=0..3 ----
    float sv = s_buf[b * SQsz + tid];                   // s[b][k=tid]
    float acc[4];
#pragma unroll
    for (int j = 0; j < 4; ++j) {
        int o = ((i << 2) | j) * Csz + c;
        acc[j] = sv * expand_w[(size_t)o * SQsz + tid];
    }
#pragma unroll
    for (int off = 32; off >= 1; off >>= 1) {
#pragma unroll
        for (int j = 0; j < 4; ++j)
            acc[j] += __shfl_xor(acc[j], off, 64);
    }
    __shared__ float cr[4][4];        // [wave][j]
    __shared__ float gates[4];
    if (lane == 0) {
#pragma unroll
        for (int j = 0; j < 4; ++j) cr[wid][j] = acc[j];
    }
    __syncthreads();
    if (tid < 4) {
        int o = ((i << 2) | tid) * Csz + c;
        float x = expand_b[o] + cr[0][tid] + cr[1][tid] + cr[2][tid] + cr[3][tid];
        gates[tid] = 1.0f / (1.0f + expf(-x));
    }
    __syncthreads();

    // ---- streaming: 4 float4 per thread; j = (tid&63)>>4 constant ----
    float gate = gates[lane >> 4];
#pragma unroll
    for (int it = 0; it < 4; ++it) {
        unsigned int idx = base_f4 + (unsigned int)tid + (unsigned int)it * 256u;
        f32x4 v = *(const f32x4*)(t + (size_t)idx * 4);
        f32x4 r;
        r.x = v.x * gate;
        r.y = v.y * gate;
        r.z = v.z * gate;
        r.w = v.w * gate;
        *(f32x4*)(out + (size_t)idx * 4) = r;
    }
}

extern "C" void kernel_launch(void* const* d_in, const int* in_sizes, int n_in,
                              void* d_out, int out_size, void* d_ws, size_t ws_size,
                              hipStream_t stream) {
    const float* t        = (const float*)d_in[0];
    const float* reduce_w = (const float*)d_in[1];
    const float* reduce_b = (const float*)d_in[2];
    const float* expand_w = (const float*)d_in[3];
    const float* expand_b = (const float*)d_in[4];
    float* out = (float*)d_out;

    float* pooled = (float*)d_ws;                 // 8*1024 fp32 = 32 KB
    float* s_buf  = pooled + Bsz * C16;           // 8*256  fp32 =  8 KB

    pool_kernel  <<<Bsz * Csz * 16, 256, 0, stream>>>(t, pooled);
    reduce_kernel<<<SQsz,          1024, 0, stream>>>(pooled, reduce_w, reduce_b, s_buf);
    scale_kernel <<<8192,           256, 0, stream>>>(t, s_buf, expand_w, expand_b, out);
}

// Round 7
// 259.255 us; speedup vs baseline: 1.5517x; 1.0052x over previous
//
#include <hip/hip_runtime.h>
#include <math.h>

// SE4 squeeze-excite, B=8, C=64, H=W=256, 4x4 patch grid (64x64 patches), SQ=256.
// ALL I/O float32. fp32 compute.
//
// R10 = R9 + ONE change: scale's out-store is nontemporal (loads stay cached).
// Theory: t(134MB) + out(134MB) = 268MB > 256MB L3; regular out stores allocate
// in L3 and evict not-yet-read t lines, pushing part of t's 2nd read to HBM.
// NT store keeps out from polluting L3. Completes the 2x2:
//   (plain,plain)=257.5 (R3) | (NT,NT)=260-262 (R5/R8) | (plain,NT)=THIS.
// Accounting (R7 + fills): window = ~160us poison fills + ~20us memset +
// ~80us our kernels (floor ~55). This targets the scale L3-thrash slice.

#define Bsz 8
#define Csz 64
#define Hsz 256
#define Wsz 256
#define SQsz 256
#define C16 1024   // 16*C

typedef float f32x4 __attribute__((ext_vector_type(4)));

// ---------------- kernel 1: patch pooling ----------------
// grid = B*C*16 = 8192 blocks of 256 threads. p = bid & 15 (= i*4+j), bc = bid>>4.
// Patch: 64 rows x 64 cols fp32 = 1024 float4 groups; each thread sums 4 groups.
// Regular (caching) loads on purpose: t must land in L3 for scale_kernel.
__global__ __launch_bounds__(256) void pool_kernel(const float* __restrict__ t,
                                                   float* __restrict__ pooled) {
    int bid = blockIdx.x;
    int p   = bid & 15;
    int bc  = bid >> 4;          // b*C + c
    int i   = p >> 2, j = p & 3;
    const float* base = t + (((size_t)bc * Hsz + (size_t)i * 64) * Wsz + (size_t)j * 64);
    int tid = threadIdx.x;
    float sum = 0.f;
#pragma unroll
    for (int k = 0; k < 4; ++k) {
        int g    = tid + k * 256;          // 0..1023
        int row  = g >> 4;
        int col4 = g & 15;
        f32x4 v = *(const f32x4*)(base + (size_t)row * Wsz + col4 * 4);
        sum += v.x + v.y + v.z + v.w;
    }
#pragma unroll
    for (int off = 32; off > 0; off >>= 1) sum += __shfl_down(sum, off, 64);
    __shared__ float wsum[4];
    if ((tid & 63) == 0) wsum[tid >> 6] = sum;
    __syncthreads();
    if (tid == 0) {
        float s = wsum[0] + wsum[1] + wsum[2] + wsum[3];
        int b = bc >> 6;          // /C
        int c = bc & 63;
        pooled[b * C16 + p * Csz + c] = s * (1.0f / 4096.0f);
    }
}

// ---------------- kernel 2: s = mish(pooled @ reduce_w^T + reduce_b) ----------------
// grid = 256 blocks (one per output o) x 1024 threads: k = tid, one element per
// thread, 9-deep chain, 16 waves/CU. s layout: s_buf[b*256 + o].
__global__ __launch_bounds__(1024) void reduce_kernel(const float* __restrict__ pooled,
                                                      const float* __restrict__ reduce_w,
                                                      const float* __restrict__ reduce_b,
                                                      float* __restrict__ s_out) {
    int o   = blockIdx.x;
    int tid = threadIdx.x;          // 0..1023 == k
    int w   = tid >> 6;             // wave 0..15
    int l   = tid & 63;
    float wv = reduce_w[(size_t)o * C16 + tid];
    float acc[Bsz];
#pragma unroll
    for (int b = 0; b < Bsz; ++b)
        acc[b] = wv * pooled[b * C16 + tid];
#pragma unroll
    for (int off = 32; off > 0; off >>= 1) {
#pragma unroll
        for (int b = 0; b < Bsz; ++b)
            acc[b] += __shfl_xor(acc[b], off, 64);
    }
    __shared__ float red[16][Bsz];
    if (l == 0) {
#pragma unroll
        for (int b = 0; b < Bsz; ++b) red[w][b] = acc[b];
    }
    __syncthreads();
    if (tid < Bsz) {
        float x = reduce_b[o];
#pragma unroll
        for (int q = 0; q < 16; ++q) x += red[q][tid];
        float sp = (x > 15.f) ? x : log1pf(expf(x));
        s_out[tid * SQsz + o] = x * tanhf(sp);
    }
}

// ---------------- kernel 3: out = t * sigmoid(s @ expand_w^T + expand_b) ----------------
// grid = 8192 blocks x 256 threads. Block covers 4096 contiguous floats =
// 16 h-rows, aligned -> single (b, c, i); only 4 gates needed (j = 0..3).
// Gate recompute in-block: thread tid holds k=tid; 4 dots over L2-hot
// s_buf row (1 KB) and expand_w rows (4 KB); butterfly + LDS combine.
// Streaming: plain t loads (L3-hit), NONTEMPORAL out stores (no L3 pollution).
__global__ __launch_bounds__(256) void scale_kernel(const float* __restrict__ t,
                                                    const float* __restrict__ s_buf,
                                                    const float* __restrict__ expand_w,
                                                    const float* __restrict__ expand_b,
                                                    float* __restrict__ out) {
    int bid  = blockIdx.x;               // 0..8191
    int tid  = threadIdx.x;              // 0..255
    int lane = tid & 63;
    int wid  = tid >> 6;

    unsigned int base_f4 = (unsigned int)bid * 1024u;   // float4 group index base
    int b  = base_f4 >> 20;                             // 2^20 f4 per batch
    int c  = (base_f4 >> 14) & 63;                      // 2^14 f4 per channel
    int i  = ((base_f4 >> 6) & 255) >> 6;               // patch-row of this slab

    // ---- gate recompute: o_j = (i*4+j)*64 + c, j=0..3 ----
    float sv = s_buf[b * SQsz + tid];                   // s[b][k=tid]
    float acc[4];
#pragma unroll
    for (int j = 0; j < 4; ++j) {
        int o = ((i << 2) | j) * Csz + c;
        acc[j] = sv * expand_w[(size_t)o * SQsz + tid];
    }
#pragma unroll
    for (int off = 32; off >= 1; off >>= 1) {
#pragma unroll
        for (int j = 0; j < 4; ++j)
            acc[j] += __shfl_xor(acc[j], off, 64);
    }
    __shared__ float cr[4][4];        // [wave][j]
    __shared__ float gates[4];
    if (lane == 0) {
#pragma unroll
        for (int j = 0; j < 4; ++j) cr[wid][j] = acc[j];
    }
    __syncthreads();
    if (tid < 4) {
        int o = ((i << 2) | tid) * Csz + c;
        float x = expand_b[o] + cr[0][tid] + cr[1][tid] + cr[2][tid] + cr[3][tid];
        gates[tid] = 1.0f / (1.0f + expf(-x));
    }
    __syncthreads();

    // ---- streaming: 4 float4 per thread; j = (tid&63)>>4 constant ----
    float gate = gates[lane >> 4];
#pragma unroll
    for (int it = 0; it < 4; ++it) {
        unsigned int idx = base_f4 + (unsigned int)tid + (unsigned int)it * 256u;
        f32x4 v = *(const f32x4*)(t + (size_t)idx * 4);
        f32x4 r;
        r.x = v.x * gate;
        r.y = v.y * gate;
        r.z = v.z * gate;
        r.w = v.w * gate;
        __builtin_nontemporal_store(r, (f32x4*)(out + (size_t)idx * 4));
    }
}

extern "C" void kernel_launch(void* const* d_in, const int* in_sizes, int n_in,
                              void* d_out, int out_size, void* d_ws, size_t ws_size,
                              hipStream_t stream) {
    const float* t        = (const float*)d_in[0];
    const float* reduce_w = (const float*)d_in[1];
    const float* reduce_b = (const float*)d_in[2];
    const float* expand_w = (const float*)d_in[3];
    const float* expand_b = (const float*)d_in[4];
    float* out = (float*)d_out;

    float* pooled = (float*)d_ws;                 // 8*1024 fp32 = 32 KB
    float* s_buf  = pooled + Bsz * C16;           // 8*256  fp32 =  8 KB

    pool_kernel  <<<Bsz * Csz * 16, 256, 0, stream>>>(t, pooled);
    reduce_kernel<<<SQsz,          1024, 0, stream>>>(pooled, reduce_w, reduce_b, s_buf);
    scale_kernel <<<8192,           256, 0, stream>>>(t, s_buf, expand_w, expand_b, out);
}